// Round 13
// baseline (69.972 us; speedup 1.0000x reference)
//
#include <hip/hip_runtime.h>
#include <hip/hip_fp16.h>

#define N 224        // image size
#define M 32         // CUT (number of sine modes)
#define NPIX (N * N) // 50176
#define NPLANE 384   // 128 * 3
#define PLT 128      // planes per remap group
#define NPGRP 3      // 384 / 128
#define TTILE 4704   // transpose tiles: (50176/64 px) * (384/64 planes)
#define NPT 6        // plane tiles (384/64)
#define RPX 64       // remap pixel tile
#define NCHUNK (NPIX / RPX)   // 784
#define NXCD 8
#define CPX (NCHUNK / NXCD)   // 98
#define PI_F 3.14159265358979323846f

typedef float vfloat4 __attribute__((ext_vector_type(4)));
typedef float vfloat2 __attribute__((ext_vector_type(2)));

// --- Fused stage 1+2 (round-11 bodies; occupancy-tuned launch) -------------
// Grid = 4928 = 224*22 blocks: every 22nd block (b%22==0) is a FIELD row
// (spread through the grid so field's VALU work interleaves with streaming
// instead of delaying it); the other 21/22 are transpose tiles.
// LDS POOLED (union of field arrays and transpose tile): 16,640 B ->
// 8 blocks/CU (wave-cap), up from 6 (r11) / 4 (r12). The r12 counter-
// experiment showed this kernel is overlap-bound: blocks/CU is the lever.
//
// Transpose tile = 64 planes x 64 px, f32 LDS [64][65] (stride-65 words).
//   load : float4/lane, 4 plane-rows/inst (4 x 256 B segments)
//   LDS wr: scalar b32, banks (p + 4c + j) -> 2-way, free
//   LDS rd: scalar b32, banks (4c + k + P) -> 2-way, free
//   store : uint2/lane (4 fp16 planes), 4 x 128 B full lines
// xt layout: [pix][384] fp16 (plain, no permutation).
__global__ __launch_bounds__(256) void fused_field_transpose(
    const float* __restrict__ x, const float* __restrict__ Fx,
    const float* __restrict__ Fy, int4* __restrict__ tab,
    __half* __restrict__ xt)
{
    __shared__ float pool[64 * 65];   // 16,640 B, shared by both branches
    const int tid = threadIdx.x;
    const int b = blockIdx.x;

    if (b % 22 == 0) {
        // ---------------- field body (one block per row y) ----------------
        float (*cx)[M] = (float(*)[M])pool;
        float (*cy)[M] = (float(*)[M])(pool + M * M);
        float *sy = pool + 2 * M * M;

        const int y = b / 22;   // 0..223

        for (int idx = tid; idx < M * M; idx += 256) {
            const int i = idx / M, j = idx % M;
            const float fi = (float)(i + 1), fj = (float)(j + 1);
            const float r = sqrtf(fi * fi + fj * fj);
            const float e = (r < (float)M + 0.5f) ? (1.0f / r) : 0.0f;
            cx[i][j] = Fx[idx] * e;
            cy[i][j] = Fy[idx] * e;
        }
        if (tid < M) {
            const float ys = (float)y / (float)(N - 1);
            sy[tid] = sinf(PI_F * ys * (float)(tid + 1));
        }
        __syncthreads();

        if (tid >= N) return;
        const int xi = tid;

        float sx[M];
        const float xsv = (float)xi / (float)(N - 1);
#pragma unroll
        for (int i = 0; i < M; ++i)
            sx[i] = sinf(PI_F * xsv * (float)(i + 1));

        float u = 0.0f, v = 0.0f;
#pragma unroll 1
        for (int j = 0; j < M; ++j) {
            float tx = 0.0f, ty = 0.0f;
#pragma unroll
            for (int i = 0; i < M; ++i) {
                tx = fmaf(cx[i][j], sx[i], tx);
                ty = fmaf(cy[i][j], sx[i], ty);
            }
            const float syj = sy[j];
            u = fmaf(syj, tx, u);
            v = fmaf(syj, ty, v);
        }

        const float dxv = 22.4f * u;   // sqrt(T)*n = 0.1*224
        const float dyv = 22.4f * v;
        const float xn = fminf(fmaxf((float)xi + dxv, 0.0f), (float)(N - 1));
        const float yn = fminf(fmaxf((float)y + dyv, 0.0f), (float)(N - 1));
        const int bx = min((int)floorf(xn), N - 2);
        const int by = min((int)floorf(yn), N - 2);
        const float fx = xn - (float)bx;
        const float fy = yn - (float)by;

        tab[y * N + xi] = make_int4(by * N + bx,
                                    __float_as_int(fx), __float_as_int(fy), 0);
        return;
    }

    // ---------------- transpose body (r11 version, verbatim) --------------
    float (*t)[65] = (float(*)[65])pool;

    const int tb    = b - b / 22 - 1;     // 0..4703 (21 per group of 22)
    const int ptile = tb % NPT;           // plane tile 0..5
    const int xtile = tb / NPT;           // pixel tile 0..783
    const int pl0   = ptile * 64;
    const int pix0  = xtile * 64;

    const int c = tid & 15;               // 0..15
    const int q = (tid >> 4) & 3;         // 0..3
    const int w = tid >> 6;               // 0..3

    // load: plane row p = w*16 + i*4 + q; 64 px as float4 per 16 lanes
#pragma unroll
    for (int i = 0; i < 4; ++i) {
        const int p = w * 16 + i * 4 + q;
        const vfloat4 v = *(const vfloat4*)(
            x + (size_t)(pl0 + p) * NPIX + pix0 + 4 * c);
        t[p][4 * c + 0] = v.x;            // scalar writes: conflict-free
        t[p][4 * c + 1] = v.y;
        t[p][4 * c + 2] = v.z;
        t[p][4 * c + 3] = v.w;
    }
    __syncthreads();

    // read + convert + store: pixel P = w*16 + s*4 + q; planes 4c..4c+3
    __half* xo = xt + (size_t)pix0 * NPLANE + pl0;
#pragma unroll
    for (int s = 0; s < 4; ++s) {
        const int P = w * 16 + s * 4 + q;
        const float f0 = t[4 * c + 0][P];
        const float f1 = t[4 * c + 1][P];
        const float f2 = t[4 * c + 2][P];
        const float f3 = t[4 * c + 3][P];
        union { uint2 u; __half2 hh[2]; } pk;
        pk.hh[0] = __floats2half2_rn(f0, f1);
        pk.hh[1] = __floats2half2_rn(f2, f3);
        *(uint2*)&xo[(size_t)P * NPLANE + 4 * c] = pk.u;
    }
}

// --- Stage 3: remap, planes-in-lanes (round-11 version, verbatim) ----------
// Block = 64 pixels x 128 planes (one pgrp). Gather: per pixel, 4 coalesced
// half2 loads (lane = plane-pair, 256 B slice of xt[pix][384]). LDS tile
// re-transposes; stores vfloat2/lane nontemporal.
// Grid XCD-clustered: xcd owns pixel chunks [xcd*98,(xcd+1)*98) per pgrp.
__global__ __launch_bounds__(256) void remap_kernel(
    const __half* __restrict__ xt, const int4* __restrict__ tab,
    float* __restrict__ out)
{
    __shared__ float tile[RPX][130];  // writes 2-way (free), reads 4-way
    __shared__ int4 ltab[RPX];

    const int tid = threadIdx.x;
    const int w = tid >> 6, l = tid & 63;

    const int bid   = blockIdx.x;
    const int xcd   = bid & 7;
    const int local = bid >> 3;          // 0..293
    const int pg    = local / CPX;       // 0..2
    const int chunk = xcd * CPX + (local % CPX);
    const int pix0  = chunk * RPX;

    if (tid < RPX) ltab[tid] = tab[pix0 + tid];
    __syncthreads();

    const __half2* base = (const __half2*)xt;
    const int pgoff = pg * (PLT / 2);    // half2 offset within a pixel row

#pragma unroll 8
    for (int i = 0; i < 16; ++i) {
        const int pl = w * 16 + i;       // pixel-local index
        const int4 tb = ltab[pl];
        const float fx = __int_as_float(tb.y);
        const float fy = __int_as_float(tb.z);
        const float omx = 1.0f - fx, omy = 1.0f - fy;
        const float w00 = omy * omx, w01 = omy * fx;
        const float w10 = fy * omx,  w11 = fy * fx;

        const size_t b0 = (size_t)tb.x * (NPLANE / 2) + pgoff;
        const float2 c00 = __half22float2(base[b0 + l]);                          // (by,  bx)
        const float2 c01 = __half22float2(base[b0 + NPLANE / 2 + l]);             // (by,  bx+1)
        const float2 c10 = __half22float2(base[b0 + (size_t)N * (NPLANE/2) + l]); // (by+1,bx)
        const float2 c11 = __half22float2(base[b0 + (size_t)(N + 1) * (NPLANE/2) + l]); // (by+1,bx+1)

        float2 o;
        o.x = w00 * c00.x + w01 * c01.x + w10 * c10.x + w11 * c11.x;
        o.y = w00 * c00.y + w01 * c01.y + w10 * c10.y + w11 * c11.y;
        *(float2*)&tile[pl][2 * l] = o;  // planes (2l,2l+1) of pixel pl
    }
    __syncthreads();

    const int l2 = tid & 31, jg = tid >> 5;   // pixel-pair, plane-group
    float* ob = out + (size_t)pg * PLT * NPIX + pix0;
#pragma unroll
    for (int s = 0; s < 16; ++s) {
        const int j = jg * 16 + s;            // plane 0..127
        vfloat2 o2;
        o2.x = tile[2 * l2][j];
        o2.y = tile[2 * l2 + 1][j];
        __builtin_nontemporal_store(o2, (vfloat2*)&ob[(size_t)j * NPIX + 2 * l2]);
    }
}

extern "C" void kernel_launch(void* const* d_in, const int* in_sizes, int n_in,
                              void* d_out, int out_size, void* d_ws, size_t ws_size,
                              hipStream_t stream) {
    const float* x  = (const float*)d_in[0];   // [128,3,224,224]
    const float* Fx = (const float*)d_in[1];   // [32,32]
    const float* Fy = (const float*)d_in[2];   // [32,32]
    float* out = (float*)d_out;

    int4* tab = (int4*)d_ws;                               // 802,816 B
    const size_t tab_bytes = (size_t)NPIX * sizeof(int4);
    __half* xt = (__half*)((char*)d_ws + tab_bytes);       // [50176][384] fp16, 38.5 MB

    fused_field_transpose<<<TTILE + N, 256, 0, stream>>>(x, Fx, Fy, tab, xt);
    remap_kernel<<<NCHUNK * NPGRP, 256, 0, stream>>>(xt, tab, out);
}

// Round 14
// 49.676 us; speedup vs baseline: 1.4086x; 1.4086x over previous
//
#include <hip/hip_runtime.h>
#include <hip/hip_fp16.h>

#define N 224        // image size
#define M 32         // CUT (number of sine modes)
#define NPIX (N * N) // 50176
#define NPLANE 384   // 128 * 3
#define PLT 128      // planes per remap group
#define NPGRP 3      // 384 / 128
#define TTILE 4704   // transpose tiles: (50176/64 px) * (384/64 planes)
#define NPT 6        // plane tiles (384/64)
#define RPX 64       // remap pixel tile
#define NCHUNK (NPIX / RPX)   // 784
#define NXCD 8
#define CPX (NCHUNK / NXCD)   // 98
#define PI_F 3.14159265358979323846f

typedef float vfloat4 __attribute__((ext_vector_type(4)));
typedef float vfloat2 __attribute__((ext_vector_type(2)));

// --- Fused stage 1+2: EXACT round-11 configuration (field blocks [0,224)
// first, separate per-branch LDS, 64x64 tiles, plain xt[pix][384]) with ONE
// change: the tb -> (ptile, xtile) mapping is XCD-swizzled so the 6 tiles
// that write the same 64-pixel window (ptile 0..5) land on the SAME XCD,
// temporally adjacent (b, b+8, ..., b+40). Without this, each 768 B xt
// pixel-row is partially written (128 B) by 6 different non-coherent L2s.
__global__ __launch_bounds__(256) void fused_field_transpose(
    const float* __restrict__ x, const float* __restrict__ Fx,
    const float* __restrict__ Fy, int4* __restrict__ tab,
    __half* __restrict__ xt)
{
    const int tid = threadIdx.x;

    if (blockIdx.x < N) {
        // ---------------- field body (one block per row y) ----------------
        __shared__ float cx[M][M];
        __shared__ float cy[M][M];
        __shared__ float sy[M];

        const int y = blockIdx.x;

        for (int idx = tid; idx < M * M; idx += 256) {
            const int i = idx / M, j = idx % M;
            const float fi = (float)(i + 1), fj = (float)(j + 1);
            const float r = sqrtf(fi * fi + fj * fj);
            const float e = (r < (float)M + 0.5f) ? (1.0f / r) : 0.0f;
            cx[i][j] = Fx[idx] * e;
            cy[i][j] = Fy[idx] * e;
        }
        if (tid < M) {
            const float ys = (float)y / (float)(N - 1);
            sy[tid] = sinf(PI_F * ys * (float)(tid + 1));
        }
        __syncthreads();

        if (tid >= N) return;
        const int xi = tid;

        float sx[M];
        const float xsv = (float)xi / (float)(N - 1);
#pragma unroll
        for (int i = 0; i < M; ++i)
            sx[i] = sinf(PI_F * xsv * (float)(i + 1));

        float u = 0.0f, v = 0.0f;
#pragma unroll 1
        for (int j = 0; j < M; ++j) {
            float tx = 0.0f, ty = 0.0f;
#pragma unroll
            for (int i = 0; i < M; ++i) {
                tx = fmaf(cx[i][j], sx[i], tx);
                ty = fmaf(cy[i][j], sx[i], ty);
            }
            const float syj = sy[j];
            u = fmaf(syj, tx, u);
            v = fmaf(syj, ty, v);
        }

        const float dxv = 22.4f * u;   // sqrt(T)*n = 0.1*224
        const float dyv = 22.4f * v;
        const float xn = fminf(fmaxf((float)xi + dxv, 0.0f), (float)(N - 1));
        const float yn = fminf(fmaxf((float)y + dyv, 0.0f), (float)(N - 1));
        const int bx = min((int)floorf(xn), N - 2);
        const int by = min((int)floorf(yn), N - 2);
        const float fx = xn - (float)bx;
        const float fy = yn - (float)by;

        tab[y * N + xi] = make_int4(by * N + bx,
                                    __float_as_int(fx), __float_as_int(fy), 0);
        return;
    }

    // ---------------- transpose body (r11 verbatim except mapping) --------
    __shared__ float t[64][65];

    const int tb   = blockIdx.x - N;      // 0..4703
    // XCD-swizzled mapping (bijection on 4704 = 8 * 588):
    //   xcd   = tb & 7; slot = tb >> 3 (0..587)
    //   ptile = slot % 6; xtile = 8*(slot/6) + xcd
    // -> the 6 ptiles of one pixel window all run on XCD=xcd, back-to-back.
    const int xcd   = tb & 7;
    const int slot  = tb >> 3;
    const int ptile = slot % NPT;         // plane tile 0..5
    const int xtile = (slot / NPT) * NXCD + xcd;   // pixel tile 0..783
    const int pl0   = ptile * 64;
    const int pix0  = xtile * 64;

    const int c = tid & 15;               // 0..15
    const int q = (tid >> 4) & 3;         // 0..3
    const int w = tid >> 6;               // 0..3

    // load: plane row p = w*16 + i*4 + q; 64 px as float4 per 16 lanes
#pragma unroll
    for (int i = 0; i < 4; ++i) {
        const int p = w * 16 + i * 4 + q;
        const vfloat4 v = *(const vfloat4*)(
            x + (size_t)(pl0 + p) * NPIX + pix0 + 4 * c);
        t[p][4 * c + 0] = v.x;            // scalar writes: conflict-free
        t[p][4 * c + 1] = v.y;
        t[p][4 * c + 2] = v.z;
        t[p][4 * c + 3] = v.w;
    }
    __syncthreads();

    // read + convert + store: pixel P = w*16 + s*4 + q; planes 4c..4c+3
    __half* xo = xt + (size_t)pix0 * NPLANE + pl0;
#pragma unroll
    for (int s = 0; s < 4; ++s) {
        const int P = w * 16 + s * 4 + q;
        const float f0 = t[4 * c + 0][P];
        const float f1 = t[4 * c + 1][P];
        const float f2 = t[4 * c + 2][P];
        const float f3 = t[4 * c + 3][P];
        union { uint2 u; __half2 hh[2]; } pk;
        pk.hh[0] = __floats2half2_rn(f0, f1);
        pk.hh[1] = __floats2half2_rn(f2, f3);
        *(uint2*)&xo[(size_t)P * NPLANE + 4 * c] = pk.u;
    }
}

// --- Stage 3: remap, planes-in-lanes (round-11 version, verbatim) ----------
// Block = 64 pixels x 128 planes (one pgrp). Gather: per pixel, 4 coalesced
// half2 loads (lane = plane-pair, 256 B slice of xt[pix][384]). LDS tile
// re-transposes; stores vfloat2/lane nontemporal.
// Grid XCD-clustered: xcd owns pixel chunks [xcd*98,(xcd+1)*98) per pgrp.
__global__ __launch_bounds__(256) void remap_kernel(
    const __half* __restrict__ xt, const int4* __restrict__ tab,
    float* __restrict__ out)
{
    __shared__ float tile[RPX][130];  // writes 2-way (free), reads 4-way
    __shared__ int4 ltab[RPX];

    const int tid = threadIdx.x;
    const int w = tid >> 6, l = tid & 63;

    const int bid   = blockIdx.x;
    const int xcd   = bid & 7;
    const int local = bid >> 3;          // 0..293
    const int pg    = local / CPX;       // 0..2
    const int chunk = xcd * CPX + (local % CPX);
    const int pix0  = chunk * RPX;

    if (tid < RPX) ltab[tid] = tab[pix0 + tid];
    __syncthreads();

    const __half2* base = (const __half2*)xt;
    const int pgoff = pg * (PLT / 2);    // half2 offset within a pixel row

#pragma unroll 8
    for (int i = 0; i < 16; ++i) {
        const int pl = w * 16 + i;       // pixel-local index
        const int4 tb = ltab[pl];
        const float fx = __int_as_float(tb.y);
        const float fy = __int_as_float(tb.z);
        const float omx = 1.0f - fx, omy = 1.0f - fy;
        const float w00 = omy * omx, w01 = omy * fx;
        const float w10 = fy * omx,  w11 = fy * fx;

        const size_t b0 = (size_t)tb.x * (NPLANE / 2) + pgoff;
        const float2 c00 = __half22float2(base[b0 + l]);                          // (by,  bx)
        const float2 c01 = __half22float2(base[b0 + NPLANE / 2 + l]);             // (by,  bx+1)
        const float2 c10 = __half22float2(base[b0 + (size_t)N * (NPLANE/2) + l]); // (by+1,bx)
        const float2 c11 = __half22float2(base[b0 + (size_t)(N + 1) * (NPLANE/2) + l]); // (by+1,bx+1)

        float2 o;
        o.x = w00 * c00.x + w01 * c01.x + w10 * c10.x + w11 * c11.x;
        o.y = w00 * c00.y + w01 * c01.y + w10 * c10.y + w11 * c11.y;
        *(float2*)&tile[pl][2 * l] = o;  // planes (2l,2l+1) of pixel pl
    }
    __syncthreads();

    const int l2 = tid & 31, jg = tid >> 5;   // pixel-pair, plane-group
    float* ob = out + (size_t)pg * PLT * NPIX + pix0;
#pragma unroll
    for (int s = 0; s < 16; ++s) {
        const int j = jg * 16 + s;            // plane 0..127
        vfloat2 o2;
        o2.x = tile[2 * l2][j];
        o2.y = tile[2 * l2 + 1][j];
        __builtin_nontemporal_store(o2, (vfloat2*)&ob[(size_t)j * NPIX + 2 * l2]);
    }
}

extern "C" void kernel_launch(void* const* d_in, const int* in_sizes, int n_in,
                              void* d_out, int out_size, void* d_ws, size_t ws_size,
                              hipStream_t stream) {
    const float* x  = (const float*)d_in[0];   // [128,3,224,224]
    const float* Fx = (const float*)d_in[1];   // [32,32]
    const float* Fy = (const float*)d_in[2];   // [32,32]
    float* out = (float*)d_out;

    int4* tab = (int4*)d_ws;                               // 802,816 B
    const size_t tab_bytes = (size_t)NPIX * sizeof(int4);
    __half* xt = (__half*)((char*)d_ws + tab_bytes);       // [50176][384] fp16, 38.5 MB

    fused_field_transpose<<<N + TTILE, 256, 0, stream>>>(x, Fx, Fy, tab, xt);
    remap_kernel<<<NCHUNK * NPGRP, 256, 0, stream>>>(xt, tab, out);
}

// Round 15
// 48.604 us; speedup vs baseline: 1.4396x; 1.0221x over previous
//
#include <hip/hip_runtime.h>
#include <hip/hip_fp16.h>

#define N 224        // image size
#define M 32         // CUT (number of sine modes)
#define NPIX (N * N) // 50176
#define NPLANE 384   // 128 * 3
#define PLT 128      // planes per remap group
#define NPGRP 3      // 384 / 128
#define TTILE 4704   // transpose tiles: (50176/64 px) * (384/64 planes)
#define NPT 6        // plane tiles (384/64)
#define RPX 64       // remap pixel tile
#define NCHUNK (NPIX / RPX)   // 784
#define NXCD 8
#define CPX (NCHUNK / NXCD)   // 98
#define PI_F 3.14159265358979323846f

typedef float vfloat4 __attribute__((ext_vector_type(4)));
typedef float vfloat2 __attribute__((ext_vector_type(2)));

// async 16-B global->LDS DMA (no VGPR round-trip). LDS dest is wave-uniform
// base + lane*16 (linear); global source is per-lane (pre-swizzled).
#define GLOAD16(gptr, lptr)                                                   \
    __builtin_amdgcn_global_load_lds(                                         \
        (const __attribute__((address_space(1))) void*)(gptr),                \
        (__attribute__((address_space(3))) void*)(lptr), 16, 0, 0)

// --- Fused stage 1+2: round-11 config; transpose LOAD phase rebuilt as
// async global_load_lds (the r14 profile showed it latency-bound: VALU 13%,
// HBM 22%, occ 28% -> nothing saturated; ~1 load in flight per wave).
// Each wave now issues 4 x 1 KB DMA loads back-to-back (whole 16 KB tile in
// flight per block) then one barrier drain.
//
// Swizzle (both-sides, rule #21): LDS dest is linear, so tile [64][64] f32
// would be a 32-way conflict on the column-read phase. Fix: per-lane global
// source chunk = cp ^ f(row), f(row) = (row>>2)&15 (wave-uniform per inst,
// involution); read phase applies the same XOR. Read-phase banks:
// 4*((w*4+s)^c)+q -> every bank exactly 2 lanes = conflict-free.
__global__ __launch_bounds__(256) void fused_field_transpose(
    const float* __restrict__ x, const float* __restrict__ Fx,
    const float* __restrict__ Fy, int4* __restrict__ tab,
    __half* __restrict__ xt)
{
    const int tid = threadIdx.x;

    if (blockIdx.x < N) {
        // ---------------- field body (one block per row y) ----------------
        __shared__ float cx[M][M];
        __shared__ float cy[M][M];
        __shared__ float sy[M];

        const int y = blockIdx.x;

        for (int idx = tid; idx < M * M; idx += 256) {
            const int i = idx / M, j = idx % M;
            const float fi = (float)(i + 1), fj = (float)(j + 1);
            const float r = sqrtf(fi * fi + fj * fj);
            const float e = (r < (float)M + 0.5f) ? (1.0f / r) : 0.0f;
            cx[i][j] = Fx[idx] * e;
            cy[i][j] = Fy[idx] * e;
        }
        if (tid < M) {
            const float ys = (float)y / (float)(N - 1);
            sy[tid] = sinf(PI_F * ys * (float)(tid + 1));
        }
        __syncthreads();

        if (tid >= N) return;
        const int xi = tid;

        float sx[M];
        const float xsv = (float)xi / (float)(N - 1);
#pragma unroll
        for (int i = 0; i < M; ++i)
            sx[i] = sinf(PI_F * xsv * (float)(i + 1));

        float u = 0.0f, v = 0.0f;
#pragma unroll 1
        for (int j = 0; j < M; ++j) {
            float tx = 0.0f, ty = 0.0f;
#pragma unroll
            for (int i = 0; i < M; ++i) {
                tx = fmaf(cx[i][j], sx[i], tx);
                ty = fmaf(cy[i][j], sx[i], ty);
            }
            const float syj = sy[j];
            u = fmaf(syj, tx, u);
            v = fmaf(syj, ty, v);
        }

        const float dxv = 22.4f * u;   // sqrt(T)*n = 0.1*224
        const float dyv = 22.4f * v;
        const float xn = fminf(fmaxf((float)xi + dxv, 0.0f), (float)(N - 1));
        const float yn = fminf(fmaxf((float)y + dyv, 0.0f), (float)(N - 1));
        const int bx = min((int)floorf(xn), N - 2);
        const int by = min((int)floorf(yn), N - 2);
        const float fx = xn - (float)bx;
        const float fy = yn - (float)by;

        tab[y * N + xi] = make_int4(by * N + bx,
                                    __float_as_int(fx), __float_as_int(fy), 0);
        return;
    }

    // ---------------- transpose body ----------------
    __shared__ float t[64 * 64];          // 16 KB, linear, XOR-swizzled content

    const int tb    = blockIdx.x - N;     // 0..4703 (r11 plain ordering)
    const int ptile = tb % NPT;           // plane tile 0..5
    const int xtile = tb / NPT;           // pixel tile 0..783
    const int pl0   = ptile * 64;
    const int pix0  = xtile * 64;

    const int w  = tid >> 6;              // wave 0..3
    const int l  = tid & 63;
    const int r  = l >> 4;                // row-within-inst 0..3
    const int cp = l & 15;                // chunk position 0..15

    // ---- async load phase: 4 x global_load_lds_dwordx4 per wave ----
    // inst i covers rows row0..row0+3 (row0 = w*16 + i*4): 4 x 256 B global,
    // 1024 B linear LDS. f = row>>2 = 4w+i (wave-uniform). Lane reads global
    // chunk (cp ^ f) so LDS position cp holds swizzled content.
#pragma unroll
    for (int i = 0; i < 4; ++i) {
        const int row0 = w * 16 + i * 4;
        const int f    = (row0 >> 2) & 15;        // = 4w+i
        const float* g = x + (size_t)(pl0 + row0 + r) * NPIX + pix0
                           + 4 * (cp ^ f);
        GLOAD16(g, &t[row0 * 64]);
    }
    __syncthreads();   // compiler drains vmcnt before the barrier

    // ---- read + convert + store: pixel P = w*16 + s*4 + q; planes 4c..4c+3
    // LDS word for (row=4c+k, col P): (4c+k)*64 + ((P>>2)^c)*4 + (P&3).
    const int c = tid & 15;               // 0..15
    const int q = (tid >> 4) & 3;         // 0..3
    __half* xo = xt + (size_t)pix0 * NPLANE + pl0;
#pragma unroll
    for (int s = 0; s < 4; ++s) {
        const int P  = w * 16 + s * 4 + q;
        const int gc = (P >> 2) ^ c;      // swizzled chunk position
        const float f0 = t[(4 * c + 0) * 64 + gc * 4 + q];
        const float f1 = t[(4 * c + 1) * 64 + gc * 4 + q];
        const float f2 = t[(4 * c + 2) * 64 + gc * 4 + q];
        const float f3 = t[(4 * c + 3) * 64 + gc * 4 + q];
        union { uint2 u; __half2 hh[2]; } pk;
        pk.hh[0] = __floats2half2_rn(f0, f1);
        pk.hh[1] = __floats2half2_rn(f2, f3);
        *(uint2*)&xo[(size_t)P * NPLANE + 4 * c] = pk.u;
    }
}

// --- Stage 3: remap, planes-in-lanes (round-11 version, verbatim) ----------
// Block = 64 pixels x 128 planes (one pgrp). Gather: per pixel, 4 coalesced
// half2 loads (lane = plane-pair, 256 B slice of xt[pix][384]). LDS tile
// re-transposes; stores vfloat2/lane nontemporal.
// Grid XCD-clustered: xcd owns pixel chunks [xcd*98,(xcd+1)*98) per pgrp.
__global__ __launch_bounds__(256) void remap_kernel(
    const __half* __restrict__ xt, const int4* __restrict__ tab,
    float* __restrict__ out)
{
    __shared__ float tile[RPX][130];  // writes 2-way (free), reads 4-way
    __shared__ int4 ltab[RPX];

    const int tid = threadIdx.x;
    const int w = tid >> 6, l = tid & 63;

    const int bid   = blockIdx.x;
    const int xcd   = bid & 7;
    const int local = bid >> 3;          // 0..293
    const int pg    = local / CPX;       // 0..2
    const int chunk = xcd * CPX + (local % CPX);
    const int pix0  = chunk * RPX;

    if (tid < RPX) ltab[tid] = tab[pix0 + tid];
    __syncthreads();

    const __half2* base = (const __half2*)xt;
    const int pgoff = pg * (PLT / 2);    // half2 offset within a pixel row

#pragma unroll 8
    for (int i = 0; i < 16; ++i) {
        const int pl = w * 16 + i;       // pixel-local index
        const int4 tb = ltab[pl];
        const float fx = __int_as_float(tb.y);
        const float fy = __int_as_float(tb.z);
        const float omx = 1.0f - fx, omy = 1.0f - fy;
        const float w00 = omy * omx, w01 = omy * fx;
        const float w10 = fy * omx,  w11 = fy * fx;

        const size_t b0 = (size_t)tb.x * (NPLANE / 2) + pgoff;
        const float2 c00 = __half22float2(base[b0 + l]);                          // (by,  bx)
        const float2 c01 = __half22float2(base[b0 + NPLANE / 2 + l]);             // (by,  bx+1)
        const float2 c10 = __half22float2(base[b0 + (size_t)N * (NPLANE/2) + l]); // (by+1,bx)
        const float2 c11 = __half22float2(base[b0 + (size_t)(N + 1) * (NPLANE/2) + l]); // (by+1,bx+1)

        float2 o;
        o.x = w00 * c00.x + w01 * c01.x + w10 * c10.x + w11 * c11.x;
        o.y = w00 * c00.y + w01 * c01.y + w10 * c10.y + w11 * c11.y;
        *(float2*)&tile[pl][2 * l] = o;  // planes (2l,2l+1) of pixel pl
    }
    __syncthreads();

    const int l2 = tid & 31, jg = tid >> 5;   // pixel-pair, plane-group
    float* ob = out + (size_t)pg * PLT * NPIX + pix0;
#pragma unroll
    for (int s = 0; s < 16; ++s) {
        const int j = jg * 16 + s;            // plane 0..127
        vfloat2 o2;
        o2.x = tile[2 * l2][j];
        o2.y = tile[2 * l2 + 1][j];
        __builtin_nontemporal_store(o2, (vfloat2*)&ob[(size_t)j * NPIX + 2 * l2]);
    }
}

extern "C" void kernel_launch(void* const* d_in, const int* in_sizes, int n_in,
                              void* d_out, int out_size, void* d_ws, size_t ws_size,
                              hipStream_t stream) {
    const float* x  = (const float*)d_in[0];   // [128,3,224,224]
    const float* Fx = (const float*)d_in[1];   // [32,32]
    const float* Fy = (const float*)d_in[2];   // [32,32]
    float* out = (float*)d_out;

    int4* tab = (int4*)d_ws;                               // 802,816 B
    const size_t tab_bytes = (size_t)NPIX * sizeof(int4);
    __half* xt = (__half*)((char*)d_ws + tab_bytes);       // [50176][384] fp16, 38.5 MB

    fused_field_transpose<<<N + TTILE, 256, 0, stream>>>(x, Fx, Fy, tab, xt);
    remap_kernel<<<NCHUNK * NPGRP, 256, 0, stream>>>(xt, tab, out);
}